// Round 4
// baseline (308.403 us; speedup 1.0000x reference)
//
#include <hip/hip_runtime.h>
#include <hip/hip_bf16.h>
#include <math.h>

// Shapes: B=32, S=32, D=64, E=768
// out layout (floats): [0,32) agg | [32,1056) target_instance | [1056,2080) pred
//                      | [2080,2112) num_seg (as float) | [2112] cos_prior

typedef __bf16 bf16x8 __attribute__((ext_vector_type(8)));
typedef float f32x4 __attribute__((ext_vector_type(4)));

__device__ __forceinline__ unsigned short f2bf(float x) {
    unsigned int u = __float_as_uint(x);
    u = (u + 0x7fffu + ((u >> 16) & 1u)) >> 16;
    return (unsigned short)u;
}
// tanh-form GELU: x * sigmoid(1.5957691*x + 0.0713548*x^3); max abs err ~1e-3 vs erf form
__device__ __forceinline__ float gelu_fast(float x) {
    float u2 = x * fmaf(x * x, 0.0713548162726f, 1.5957691216057308f);
    return __fdividef(x, 1.0f + __expf(-u2));
}
__device__ __forceinline__ float sigmoid_fast(float x) {
    return __fdividef(1.0f, 1.0f + __expf(-x));
}
__device__ __forceinline__ float wave_sum(float v) {
    for (int o = 32; o; o >>= 1) v += __shfl_xor(v, o);
    return v;
}
__device__ __forceinline__ float wave_max(float v) {
    for (int o = 32; o; o >>= 1) v = fmaxf(v, __shfl_xor(v, o));
    return v;
}

// ---- prep: W1^T bf16, W2^T bf16, normalized-row bf16 copies (for MFMA cosine) ----
// blocks [0,288): W1 transpose ; [288,360): W2 transpose ; [360,1128): normalize rows
__global__ __launch_bounds__(256) void prep_all(const float* __restrict__ W1,
                                                const float* __restrict__ W2,
                                                const float* __restrict__ doc,
                                                const float* __restrict__ sume,
                                                unsigned short* __restrict__ W1t,
                                                unsigned short* __restrict__ W2t,
                                                unsigned short* __restrict__ dnbf,
                                                unsigned short* __restrict__ snbf) {
    int id = blockIdx.x;
    int t = threadIdx.x;
    if (id < 360) {
        __shared__ float tile[64][65];
        const float* in; unsigned short* outp; int R, C, bx, by;
        if (id < 288) { in = W1; outp = W1t; R = 1536; C = 768; bx = id % 12; by = id / 12; }
        else { int i2 = id - 288; in = W2; outp = W2t; R = 768; C = 384; bx = i2 % 6; by = i2 / 6; }
        int r0 = by * 64, c0 = bx * 64;
        #pragma unroll
        for (int p = 0; p < 16; ++p) {
            int r = p * 4 + (t >> 6), c = t & 63;
            tile[r][c] = in[(r0 + r) * C + c0 + c];
        }
        __syncthreads();
        #pragma unroll
        for (int p = 0; p < 16; ++p) {
            int cc = p * 4 + (t >> 6), rr = t & 63;
            outp[(c0 + cc) * R + r0 + rr] = f2bf(tile[rr][cc]);
        }
    } else {
        int row = (id - 360) * 4 + (t >> 6);
        int lane = t & 63;
        const float* p; unsigned short* dst;
        if (row < 2048) { p = doc + row * 768; dst = dnbf + row * 768; }
        else            { p = sume + (row - 2048) * 768; dst = snbf + (row - 2048) * 768; }
        const float* pp = p + lane * 12;
        float4 a0 = *(const float4*)(pp);
        float4 a1 = *(const float4*)(pp + 4);
        float4 a2 = *(const float4*)(pp + 8);
        float s = a0.x*a0.x + a0.y*a0.y + a0.z*a0.z + a0.w*a0.w
                + a1.x*a1.x + a1.y*a1.y + a1.z*a1.z + a1.w*a1.w
                + a2.x*a2.x + a2.y*a2.y + a2.z*a2.z + a2.w*a2.w;
        s = wave_sum(s);
        float r = rsqrtf(fmaxf(s, 1e-12f));
        unsigned short* dd = dst + lane * 12;
        dd[0]  = f2bf(a0.x * r); dd[1]  = f2bf(a0.y * r);
        dd[2]  = f2bf(a0.z * r); dd[3]  = f2bf(a0.w * r);
        dd[4]  = f2bf(a1.x * r); dd[5]  = f2bf(a1.y * r);
        dd[6]  = f2bf(a1.z * r); dd[7]  = f2bf(a1.w * r);
        dd[8]  = f2bf(a2.x * r); dd[9]  = f2bf(a2.y * r);
        dd[10] = f2bf(a2.z * r); dd[11] = f2bf(a2.w * r);
    }
}

// ---- stage-1 GEMM: [doc;sum] @ W1 -> hd/hs (fp32 out), conversion fused in staging ----
__global__ __launch_bounds__(256) void gemm1(const float* __restrict__ doc,
                                             const float* __restrict__ sume,
                                             const unsigned short* __restrict__ W1t,
                                             float* __restrict__ hd,
                                             float* __restrict__ hs) {
    __shared__ __align__(16) unsigned short Asw[128 * 64];
    __shared__ __align__(16) unsigned short Bsw[128 * 64];
    int t = threadIdx.x;
    int row0 = blockIdx.y * 128, col0 = blockIdx.x * 128;
    bool is_doc = row0 < 2048;
    const float* A = is_doc ? (doc + row0 * 768) : (sume + (row0 - 2048) * 768);
    int kbase = is_doc ? 0 : 768;
    float* O = is_doc ? (hd + row0 * 768) : (hs + (row0 - 2048) * 768);

    int l = t & 63, w = t >> 6;
    int wr = w >> 1, wc = w & 1;
    f32x4 acc[4][4];
    #pragma unroll
    for (int i = 0; i < 4; ++i)
        #pragma unroll
        for (int j = 0; j < 4; ++j) acc[i][j] = (f32x4)0.f;

    char* AswB = (char*)Asw;
    char* BswB = (char*)Bsw;
    for (int kt = 0; kt < 768; kt += 64) {
        __syncthreads();
        #pragma unroll
        for (int p = 0; p < 4; ++p) {
            int r = p * 32 + (t >> 3);
            int ko = (t & 7) * 8;
            float4 f0 = *(const float4*)(A + r * 768 + kt + ko);
            float4 f1 = *(const float4*)(A + r * 768 + kt + ko + 4);
            __hip_bfloat162 p0 = __float22bfloat162_rn(make_float2(f0.x, f0.y));
            __hip_bfloat162 p1 = __float22bfloat162_rn(make_float2(f0.z, f0.w));
            __hip_bfloat162 p2 = __float22bfloat162_rn(make_float2(f1.x, f1.y));
            __hip_bfloat162 p3 = __float22bfloat162_rn(make_float2(f1.z, f1.w));
            uint4 v = make_uint4(*(unsigned int*)&p0, *(unsigned int*)&p1,
                                 *(unsigned int*)&p2, *(unsigned int*)&p3);
            int byte = (r * 128 + ko * 2) ^ ((r & 7) << 4);
            *(uint4*)(AswB + byte) = v;
            bf16x8 bv = *(const bf16x8*)(W1t + (col0 + r) * 1536 + kbase + kt + ko);
            *(bf16x8*)(BswB + byte) = bv;
        }
        __syncthreads();
        #pragma unroll
        for (int ks = 0; ks < 2; ++ks) {
            int koff = (ks * 32 + (l >> 4) * 8) * 2;
            bf16x8 af[4], bfr[4];
            #pragma unroll
            for (int fr = 0; fr < 4; ++fr) {
                int r = wr * 64 + fr * 16 + (l & 15);
                af[fr] = *(const bf16x8*)(AswB + ((r * 128 + koff) ^ ((r & 7) << 4)));
            }
            #pragma unroll
            for (int fc = 0; fc < 4; ++fc) {
                int n = wc * 64 + fc * 16 + (l & 15);
                bfr[fc] = *(const bf16x8*)(BswB + ((n * 128 + koff) ^ ((n & 7) << 4)));
            }
            #pragma unroll
            for (int fr = 0; fr < 4; ++fr)
                #pragma unroll
                for (int fc = 0; fc < 4; ++fc)
                    acc[fr][fc] = __builtin_amdgcn_mfma_f32_16x16x32_bf16(af[fr], bfr[fc], acc[fr][fc], 0, 0, 0);
        }
    }
    #pragma unroll
    for (int fr = 0; fr < 4; ++fr)
        #pragma unroll
        for (int fc = 0; fc < 4; ++fc)
            #pragma unroll
            for (int j = 0; j < 4; ++j) {
                int r = wr * 64 + fr * 16 + (l >> 4) * 4 + j;
                int c = col0 + wc * 64 + fc * 16 + (l & 15);
                O[r * 768 + c] = acc[fr][fc][j];
            }
}

// ---- main fused kernel: single-buffered 66KB LDS -> 2 blocks/CU ----
// block = (b, s-pair); 512 threads = 8 waves (2 row-waves x 4 col-waves)
// per K-tile: barrier; stage (gelu A + B) to LDS; issue next-tile loads; barrier; MFMA
__global__ __launch_bounds__(512, 4) void score_mfma(
    const float* __restrict__ hd, const float* __restrict__ hs,
    const float* __restrict__ b1, const unsigned short* __restrict__ W2t,
    const float* __restrict__ b2, const float* __restrict__ W3,
    const float* __restrict__ b3, const int* __restrict__ ndoc,
    const int* __restrict__ nseg, float* __restrict__ out)
{
    __shared__ __align__(16) unsigned short Asw[128 * 64];   // 16 KB
    __shared__ __align__(16) unsigned short Bsw[384 * 64];   // 48 KB
    __shared__ float spart[4][128];                          // 2 KB

    int t = threadIdx.x;
    // XCD-aware swizzle: 512 blocks, 64 per XCD -> blocks sharing b stay on one XCD
    int lb = (int)(blockIdx.x & 7) * 64 + (int)(blockIdx.x >> 3);
    int b = lb >> 4, sp = lb & 15;
    int l = t & 63, w = t >> 6;
    int wr = w >> 2, wc = w & 3;
    int nd = ndoc[b], ns = nseg[b];

    f32x4 acc[4][6];
    #pragma unroll
    for (int i = 0; i < 4; ++i)
        #pragma unroll
        for (int j = 0; j < 6; ++j) acc[i][j] = (f32x4)0.f;

    const float* hdB = hd + b * 64 * 768;
    const float* hs0 = hs + (b * 32 + sp * 2) * 768;
    const float* hs1 = hs0 + 768;

    int rbase = t >> 5;          // 0..15 (A-row sub-index; rows p*16+rbase)
    int k0 = (t & 31) * 2;       // 0..62 (A k-pair)
    int bn = t >> 3;             // 0..63 (B row sub-index)
    int bko = (t & 7) * 8;       // B k-offset

    float2 hv[4]; float2 hav, hbv; bf16x8 br[6];
    char* AswB = (char*)Asw;
    char* BswB = (char*)Bsw;

#define STAGE_LOAD(KT)                                                        \
    {                                                                         \
        _Pragma("unroll")                                                     \
        for (int p = 0; p < 4; ++p)                                           \
            hv[p] = *(const float2*)(hdB + (p * 16 + rbase) * 768 + (KT) + k0); \
        float2 bb = *(const float2*)(b1 + (KT) + k0);                         \
        hav = *(const float2*)(hs0 + (KT) + k0);                              \
        hbv = *(const float2*)(hs1 + (KT) + k0);                              \
        hav.x += bb.x; hav.y += bb.y; hbv.x += bb.x; hbv.y += bb.y;           \
        _Pragma("unroll")                                                     \
        for (int q = 0; q < 6; ++q)                                           \
            br[q] = *(const bf16x8*)(W2t + (q * 64 + bn) * 768 + (KT) + bko); \
    }

#define STAGE_STORE()                                                         \
    {                                                                         \
        _Pragma("unroll")                                                     \
        for (int p = 0; p < 8; ++p) {                                         \
            float sx = (p < 4) ? hav.x : hbv.x;                               \
            float sy = (p < 4) ? hav.y : hbv.y;                               \
            float g0 = gelu_fast(hv[p & 3].x + sx);                           \
            float g1 = gelu_fast(hv[p & 3].y + sy);                           \
            __hip_bfloat162 pk = __float22bfloat162_rn(make_float2(g0, g1));  \
            int r = p * 16 + rbase;                                           \
            int byte = (r * 128 + k0 * 2) ^ ((r & 7) << 4);                   \
            *(unsigned int*)(AswB + byte) = *(unsigned int*)&pk;              \
        }                                                                     \
        _Pragma("unroll")                                                     \
        for (int q = 0; q < 6; ++q) {                                         \
            int n = q * 64 + bn;                                              \
            int byte = (n * 128 + bko * 2) ^ ((n & 7) << 4);                  \
            *(bf16x8*)(BswB + byte) = br[q];                                  \
        }                                                                     \
    }

    STAGE_LOAD(0)

    #pragma unroll 1
    for (int i = 0; i < 12; ++i) {
        __syncthreads();                 // all waves done reading LDS tile i-1
        STAGE_STORE()                    // write tile i (waits on its loads)
        if (i < 11) STAGE_LOAD((i + 1) * 64)   // next-tile loads fly during MFMA
        __syncthreads();                 // tile i visible
        #pragma unroll
        for (int ks = 0; ks < 2; ++ks) {
            int koff = (ks * 32 + (l >> 4) * 8) * 2;
            bf16x8 af[4], bfr[6];
            #pragma unroll
            for (int fr = 0; fr < 4; ++fr) {
                int r = wr * 64 + fr * 16 + (l & 15);
                af[fr] = *(const bf16x8*)(AswB + ((r * 128 + koff) ^ ((r & 7) << 4)));
            }
            #pragma unroll
            for (int fc = 0; fc < 6; ++fc) {
                int n = wc * 96 + fc * 16 + (l & 15);
                bfr[fc] = *(const bf16x8*)(BswB + ((n * 128 + koff) ^ ((n & 7) << 4)));
            }
            #pragma unroll
            for (int fr = 0; fr < 4; ++fr)
                #pragma unroll
                for (int fc = 0; fc < 6; ++fc)
                    acc[fr][fc] = __builtin_amdgcn_mfma_f32_16x16x32_bf16(af[fr], bfr[fc], acc[fr][fc], 0, 0, 0);
        }
    }
#undef STAGE_LOAD
#undef STAGE_STORE

    // epilogue: h2 = gelu(acc + b2); score = sigmoid(h2 . W3 + b3); masked max over d
    float b2v[6], w3v[6];
    #pragma unroll
    for (int fc = 0; fc < 6; ++fc) {
        int col = wc * 96 + fc * 16 + (l & 15);
        b2v[fc] = b2[col];
        w3v[fc] = W3[col];
    }
    #pragma unroll
    for (int fr = 0; fr < 4; ++fr) {
        #pragma unroll
        for (int j = 0; j < 4; ++j) {
            float pr = 0.f;
            #pragma unroll
            for (int fc = 0; fc < 6; ++fc)
                pr += gelu_fast(acc[fr][fc][j] + b2v[fc]) * w3v[fc];
            pr += __shfl_xor(pr, 1);
            pr += __shfl_xor(pr, 2);
            pr += __shfl_xor(pr, 4);
            pr += __shfl_xor(pr, 8);
            if ((l & 15) == 0)
                spart[wc][wr * 64 + fr * 16 + (l >> 4) * 4 + j] = pr;
        }
    }
    __syncthreads();
    if (t < 128) {
        int row = t;
        float v = spart[0][row] + spart[1][row] + spart[2][row] + spart[3][row] + b3[0];
        float sc = sigmoid_fast(v);
        int d = row & 63, sl = row >> 6;
        float m = (d < nd) ? sc : 0.f;
        m = wave_max(m);
        if ((t & 63) == 0) {
            float segw = (ns > 10) ? 1.f : 100.f;
            out[1056 + b * 32 + sp * 2 + sl] = segw * m;
        }
    }
}

// ---- cosine via MFMA on normalized bf16 rows: dscos[b,s] = max_{d<nd} (1-dot)/2 ----
// 32 blocks (one per b), 256 threads = 4 waves; wave w owns d-slice [w*16, w*16+16)
__global__ __launch_bounds__(256) void cos_mfma(const unsigned short* __restrict__ dnbf,
                                                const unsigned short* __restrict__ snbf,
                                                const int* __restrict__ ndoc,
                                                float* __restrict__ dscos) {
    __shared__ float sred[4][32];
    int t = threadIdx.x, l = t & 63, w = t >> 6;
    int b = blockIdx.x;
    const unsigned short* sb = snbf + b * 32 * 768;
    const unsigned short* db = dnbf + b * 64 * 768;
    int arow = l & 15, ak = (l >> 4) * 8;
    int d0 = w * 16;
    f32x4 acc0 = (f32x4)0.f, acc1 = (f32x4)0.f;
    #pragma unroll
    for (int k = 0; k < 768; k += 32) {
        bf16x8 a0 = *(const bf16x8*)(sb + arow * 768 + k + ak);
        bf16x8 a1 = *(const bf16x8*)(sb + (16 + arow) * 768 + k + ak);
        bf16x8 bb = *(const bf16x8*)(db + (d0 + arow) * 768 + k + ak);
        acc0 = __builtin_amdgcn_mfma_f32_16x16x32_bf16(a0, bb, acc0, 0, 0, 0);
        acc1 = __builtin_amdgcn_mfma_f32_16x16x32_bf16(a1, bb, acc1, 0, 0, 0);
    }
    int nd = ndoc[b];
    int d = d0 + (l & 15);
    float v0[4], v1[4];
    #pragma unroll
    for (int j = 0; j < 4; ++j) {
        v0[j] = (d < nd) ? (1.f - acc0[j]) * 0.5f : 0.f;
        v1[j] = (d < nd) ? (1.f - acc1[j]) * 0.5f : 0.f;
    }
    #pragma unroll
    for (int o = 1; o < 16; o <<= 1) {
        #pragma unroll
        for (int j = 0; j < 4; ++j) {
            v0[j] = fmaxf(v0[j], __shfl_xor(v0[j], o));
            v1[j] = fmaxf(v1[j], __shfl_xor(v1[j], o));
        }
    }
    if ((l & 15) == 0) {
        int srow = (l >> 4) * 4;
        #pragma unroll
        for (int j = 0; j < 4; ++j) {
            sred[w][srow + j] = v0[j];
            sred[w][16 + srow + j] = v1[j];
        }
    }
    __syncthreads();
    if (t < 32)
        dscos[b * 32 + t] = fmaxf(fmaxf(sred[0][t], sred[1][t]),
                                  fmaxf(sred[2][t], sred[3][t]));
}

// ---- finish: passthrough outputs + cos_prior reduction ----
__global__ __launch_bounds__(1024) void finish_k(const float* __restrict__ agg,
                                                 const float* __restrict__ tinst,
                                                 const int* __restrict__ nseg,
                                                 const float* __restrict__ dscos,
                                                 float* __restrict__ out) {
    __shared__ float red[16];
    int t = threadIdx.x, lane = t & 63, w = t >> 6;
    int b = t >> 5, s = t & 31;
    int ns = nseg[b];
    out[32 + t] = (s < ns) ? tinst[t] : 1.0f;
    if (t < 32) {
        out[t] = agg[t];
        out[2080 + t] = (float)nseg[t];
    }
    float pred = out[1056 + t];
    float v = (s < ns) ? fabsf(dscos[t] - pred) / (float)ns : 0.f;
    v = wave_sum(v);
    if (lane == 0) red[w] = v;
    __syncthreads();
    if (w == 0) {
        float x = (lane < 16) ? red[lane] : 0.f;
        x = wave_sum(x);
        if (lane == 0) out[2112] = x * (1.f / 32.f);
    }
}

extern "C" void kernel_launch(void* const* d_in, const int* in_sizes, int n_in,
                              void* d_out, int out_size, void* d_ws, size_t ws_size,
                              hipStream_t stream) {
    const float* doc   = (const float*)d_in[0];   // [32,64,768]
    const float* sume  = (const float*)d_in[1];   // [32,32,768]
    const int*   ndoc  = (const int*)d_in[2];     // [32]
    const int*   nseg  = (const int*)d_in[3];     // [32]
    const float* agg   = (const float*)d_in[4];   // [32]
    const float* tinst = (const float*)d_in[5];   // [32,32]
    const float* W1    = (const float*)d_in[6];   // [1536,768]
    const float* b1    = (const float*)d_in[7];   // [768]
    const float* W2    = (const float*)d_in[8];   // [768,384]
    const float* b2    = (const float*)d_in[9];   // [384]
    const float* W3    = (const float*)d_in[10];  // [384,1]
    const float* b3    = (const float*)d_in[11];  // [1]
    float* out = (float*)d_out;
    char* ws = (char*)d_ws;

    float* hd    = (float*)(ws);                              // 2048*768 f32
    float* hs    = (float*)(ws + 6291456);                    // 1024*768 f32
    unsigned short* W1t  = (unsigned short*)(ws + 9437184);   // [768][1536] bf16
    unsigned short* W2t  = (unsigned short*)(ws + 11796480);  // [384][768] bf16
    unsigned short* dnbf = (unsigned short*)(ws + 12386304);  // [2048][768] bf16 normalized
    unsigned short* snbf = (unsigned short*)(ws + 15532032);  // [1024][768] bf16 normalized
    float* dscos = (float*)(ws + 17104896);                   // 1024 f32

    prep_all<<<1128, 256, 0, stream>>>(W1, W2, doc, sume, W1t, W2t, dnbf, snbf);
    gemm1<<<dim3(6, 24), 256, 0, stream>>>(doc, sume, W1t, hd, hs);
    score_mfma<<<512, 512, 0, stream>>>(hd, hs, b1, W2t, b2, W3, b3, ndoc, nseg, out);
    cos_mfma<<<32, 256, 0, stream>>>(dnbf, snbf, ndoc, dscos);
    finish_k<<<1, 1024, 0, stream>>>(agg, tinst, nseg, dscos, out);
}

// Round 5
// 143.382 us; speedup vs baseline: 2.1509x; 2.1509x over previous
//
#include <hip/hip_runtime.h>
#include <hip/hip_bf16.h>
#include <math.h>

// Shapes: B=32, S=32, D=64, E=768
// out layout (floats): [0,32) agg | [32,1056) target_instance | [1056,2080) pred
//                      | [2080,2112) num_seg (as float) | [2112] cos_prior

typedef __bf16 bf16x8 __attribute__((ext_vector_type(8)));
typedef float f32x4 __attribute__((ext_vector_type(4)));

__device__ __forceinline__ unsigned short f2bf(float x) {
    unsigned int u = __float_as_uint(x);
    u = (u + 0x7fffu + ((u >> 16) & 1u)) >> 16;
    return (unsigned short)u;
}
// tanh-form GELU: x * sigmoid(1.5957691*x + 0.0713548*x^3); max abs err ~1e-3 vs erf form
__device__ __forceinline__ float gelu_fast(float x) {
    float u2 = x * fmaf(x * x, 0.0713548162726f, 1.5957691216057308f);
    return __fdividef(x, 1.0f + __expf(-u2));
}
__device__ __forceinline__ float sigmoid_fast(float x) {
    return __fdividef(1.0f, 1.0f + __expf(-x));
}
__device__ __forceinline__ float wave_sum(float v) {
    for (int o = 32; o; o >>= 1) v += __shfl_xor(v, o);
    return v;
}
__device__ __forceinline__ float wave_max(float v) {
    for (int o = 32; o; o >>= 1) v = fmaxf(v, __shfl_xor(v, o));
    return v;
}

// ---- prep: W1^T bf16, W2^T bf16, normalized-row bf16 copies (for MFMA cosine) ----
// blocks [0,288): W1 transpose ; [288,360): W2 transpose ; [360,1128): normalize rows
__global__ __launch_bounds__(256) void prep_all(const float* __restrict__ W1,
                                                const float* __restrict__ W2,
                                                const float* __restrict__ doc,
                                                const float* __restrict__ sume,
                                                unsigned short* __restrict__ W1t,
                                                unsigned short* __restrict__ W2t,
                                                unsigned short* __restrict__ dnbf,
                                                unsigned short* __restrict__ snbf) {
    int id = blockIdx.x;
    int t = threadIdx.x;
    if (id < 360) {
        __shared__ float tile[64][65];
        const float* in; unsigned short* outp; int R, C, bx, by;
        if (id < 288) { in = W1; outp = W1t; R = 1536; C = 768; bx = id % 12; by = id / 12; }
        else { int i2 = id - 288; in = W2; outp = W2t; R = 768; C = 384; bx = i2 % 6; by = i2 / 6; }
        int r0 = by * 64, c0 = bx * 64;
        #pragma unroll
        for (int p = 0; p < 16; ++p) {
            int r = p * 4 + (t >> 6), c = t & 63;
            tile[r][c] = in[(r0 + r) * C + c0 + c];
        }
        __syncthreads();
        #pragma unroll
        for (int p = 0; p < 16; ++p) {
            int cc = p * 4 + (t >> 6), rr = t & 63;
            outp[(c0 + cc) * R + r0 + rr] = f2bf(tile[rr][cc]);
        }
    } else {
        int row = (id - 360) * 4 + (t >> 6);
        int lane = t & 63;
        const float* p; unsigned short* dst;
        if (row < 2048) { p = doc + row * 768; dst = dnbf + row * 768; }
        else            { p = sume + (row - 2048) * 768; dst = snbf + (row - 2048) * 768; }
        const float* pp = p + lane * 12;
        float4 a0 = *(const float4*)(pp);
        float4 a1 = *(const float4*)(pp + 4);
        float4 a2 = *(const float4*)(pp + 8);
        float s = a0.x*a0.x + a0.y*a0.y + a0.z*a0.z + a0.w*a0.w
                + a1.x*a1.x + a1.y*a1.y + a1.z*a1.z + a1.w*a1.w
                + a2.x*a2.x + a2.y*a2.y + a2.z*a2.z + a2.w*a2.w;
        s = wave_sum(s);
        float r = rsqrtf(fmaxf(s, 1e-12f));
        unsigned short* dd = dst + lane * 12;
        dd[0]  = f2bf(a0.x * r); dd[1]  = f2bf(a0.y * r);
        dd[2]  = f2bf(a0.z * r); dd[3]  = f2bf(a0.w * r);
        dd[4]  = f2bf(a1.x * r); dd[5]  = f2bf(a1.y * r);
        dd[6]  = f2bf(a1.z * r); dd[7]  = f2bf(a1.w * r);
        dd[8]  = f2bf(a2.x * r); dd[9]  = f2bf(a2.y * r);
        dd[10] = f2bf(a2.z * r); dd[11] = f2bf(a2.w * r);
    }
}

// ---- stage-1 GEMM: [doc;sum] @ W1 -> hd/hs (fp32 out), conversion fused in staging ----
__global__ __launch_bounds__(256) void gemm1(const float* __restrict__ doc,
                                             const float* __restrict__ sume,
                                             const unsigned short* __restrict__ W1t,
                                             float* __restrict__ hd,
                                             float* __restrict__ hs) {
    __shared__ __align__(16) unsigned short Asw[128 * 64];
    __shared__ __align__(16) unsigned short Bsw[128 * 64];
    int t = threadIdx.x;
    int row0 = blockIdx.y * 128, col0 = blockIdx.x * 128;
    bool is_doc = row0 < 2048;
    const float* A = is_doc ? (doc + row0 * 768) : (sume + (row0 - 2048) * 768);
    int kbase = is_doc ? 0 : 768;
    float* O = is_doc ? (hd + row0 * 768) : (hs + (row0 - 2048) * 768);

    int l = t & 63, w = t >> 6;
    int wr = w >> 1, wc = w & 1;
    f32x4 acc[4][4];
    #pragma unroll
    for (int i = 0; i < 4; ++i)
        #pragma unroll
        for (int j = 0; j < 4; ++j) acc[i][j] = (f32x4)0.f;

    char* AswB = (char*)Asw;
    char* BswB = (char*)Bsw;
    for (int kt = 0; kt < 768; kt += 64) {
        __syncthreads();
        #pragma unroll
        for (int p = 0; p < 4; ++p) {
            int r = p * 32 + (t >> 3);
            int ko = (t & 7) * 8;
            float4 f0 = *(const float4*)(A + r * 768 + kt + ko);
            float4 f1 = *(const float4*)(A + r * 768 + kt + ko + 4);
            __hip_bfloat162 p0 = __float22bfloat162_rn(make_float2(f0.x, f0.y));
            __hip_bfloat162 p1 = __float22bfloat162_rn(make_float2(f0.z, f0.w));
            __hip_bfloat162 p2 = __float22bfloat162_rn(make_float2(f1.x, f1.y));
            __hip_bfloat162 p3 = __float22bfloat162_rn(make_float2(f1.z, f1.w));
            uint4 v = make_uint4(*(unsigned int*)&p0, *(unsigned int*)&p1,
                                 *(unsigned int*)&p2, *(unsigned int*)&p3);
            int byte = (r * 128 + ko * 2) ^ ((r & 7) << 4);
            *(uint4*)(AswB + byte) = v;
            bf16x8 bv = *(const bf16x8*)(W1t + (col0 + r) * 1536 + kbase + kt + ko);
            *(bf16x8*)(BswB + byte) = bv;
        }
        __syncthreads();
        #pragma unroll
        for (int ks = 0; ks < 2; ++ks) {
            int koff = (ks * 32 + (l >> 4) * 8) * 2;
            bf16x8 af[4], bfr[4];
            #pragma unroll
            for (int fr = 0; fr < 4; ++fr) {
                int r = wr * 64 + fr * 16 + (l & 15);
                af[fr] = *(const bf16x8*)(AswB + ((r * 128 + koff) ^ ((r & 7) << 4)));
            }
            #pragma unroll
            for (int fc = 0; fc < 4; ++fc) {
                int n = wc * 64 + fc * 16 + (l & 15);
                bfr[fc] = *(const bf16x8*)(BswB + ((n * 128 + koff) ^ ((n & 7) << 4)));
            }
            #pragma unroll
            for (int fr = 0; fr < 4; ++fr)
                #pragma unroll
                for (int fc = 0; fc < 4; ++fc)
                    acc[fr][fc] = __builtin_amdgcn_mfma_f32_16x16x32_bf16(af[fr], bfr[fc], acc[fr][fc], 0, 0, 0);
        }
    }
    #pragma unroll
    for (int fr = 0; fr < 4; ++fr)
        #pragma unroll
        for (int fc = 0; fc < 4; ++fc)
            #pragma unroll
            for (int j = 0; j < 4; ++j) {
                int r = wr * 64 + fr * 16 + (l >> 4) * 4 + j;
                int c = col0 + wc * 64 + fc * 16 + (l & 15);
                O[r * 768 + c] = acc[fr][fc][j];
            }
}

// ---- main fused kernel: one block per (b,s); 8 col-waves of 64rows x 48cols ----
// A (gelu(hd+hs+b1), 64x64 bf16) staged in 8KB LDS; W2^T fragments read DIRECTLY
// from global (L2-resident, one 128B line per (n,kt) shared by both ks-frags).
// acc = 12 x f32x4 = 48 regs/thread -> no spill, ~3 waves/SIMD occupancy.
__global__ __launch_bounds__(512, 2) void score_mfma(
    const float* __restrict__ hd, const float* __restrict__ hs,
    const float* __restrict__ b1, const unsigned short* __restrict__ W2t,
    const float* __restrict__ b2, const float* __restrict__ W3,
    const float* __restrict__ b3, const int* __restrict__ ndoc,
    const int* __restrict__ nseg, float* __restrict__ out)
{
    __shared__ __align__(16) unsigned short Asw[64 * 64];    // 8 KB
    __shared__ float spart[8][64];                           // 2 KB

    int t = threadIdx.x;
    // XCD-aware swizzle: 1024 blocks, 128 per XCD; the 32 s-blocks of one b share an XCD
    int lb = (int)(blockIdx.x & 7) * 128 + (int)(blockIdx.x >> 3);
    int b = lb >> 5, s = lb & 31;
    int l = t & 63, w = t >> 6;                // w = col-wave 0..7
    int nd = ndoc[b], ns = nseg[b];

    f32x4 acc[4][3];
    #pragma unroll
    for (int i = 0; i < 4; ++i)
        #pragma unroll
        for (int j = 0; j < 3; ++j) acc[i][j] = (f32x4)0.f;

    const float* hdB = hd + b * 64 * 768;
    const float* hsr = hs + (b * 32 + s) * 768;

    int rbase = t >> 5;          // 0..15 (A-row sub-index; rows p*16+rbase)
    int k0 = (t & 31) * 2;       // 0..62 (A k-pair)
    char* AswB = (char*)Asw;

    // B-fragment addresses (fixed per thread; advance by kt)
    const unsigned short* bptr[3];
    #pragma unroll
    for (int fc = 0; fc < 3; ++fc) {
        int n = w * 48 + fc * 16 + (l & 15);
        bptr[fc] = W2t + n * 768 + (l >> 4) * 8;
    }

    float2 hv[4]; float2 hav;
    bf16x8 bfr[2][3];

#define STAGE_LOAD(KT)                                                          \
    {                                                                           \
        _Pragma("unroll")                                                       \
        for (int p = 0; p < 4; ++p)                                             \
            hv[p] = *(const float2*)(hdB + (p * 16 + rbase) * 768 + (KT) + k0); \
        float2 bb = *(const float2*)(b1 + (KT) + k0);                           \
        hav = *(const float2*)(hsr + (KT) + k0);                                \
        hav.x += bb.x; hav.y += bb.y;                                           \
    }

#define B_LOAD(KT)                                                              \
    {                                                                           \
        _Pragma("unroll")                                                       \
        for (int ks = 0; ks < 2; ++ks)                                          \
            _Pragma("unroll")                                                   \
            for (int fc = 0; fc < 3; ++fc)                                      \
                bfr[ks][fc] = *(const bf16x8*)(bptr[fc] + (KT) + ks * 32);      \
    }

#define STAGE_STORE()                                                           \
    {                                                                           \
        _Pragma("unroll")                                                       \
        for (int p = 0; p < 4; ++p) {                                           \
            float g0 = gelu_fast(hv[p].x + hav.x);                              \
            float g1 = gelu_fast(hv[p].y + hav.y);                              \
            __hip_bfloat162 pk = __float22bfloat162_rn(make_float2(g0, g1));    \
            int r = p * 16 + rbase;                                             \
            int byte = (r * 128 + k0 * 2) ^ ((r & 7) << 4);                     \
            *(unsigned int*)(AswB + byte) = *(unsigned int*)&pk;                \
        }                                                                       \
    }

    STAGE_LOAD(0)
    B_LOAD(0)

    #pragma unroll 1
    for (int i = 0; i < 12; ++i) {
        __syncthreads();                 // all waves done reading LDS tile i-1
        STAGE_STORE()                    // write A tile i
        if (i < 11) STAGE_LOAD((i + 1) * 64)   // next-tile A loads fly during MFMA
        __syncthreads();                 // tile i visible
        #pragma unroll
        for (int ks = 0; ks < 2; ++ks) {
            int koff = (ks * 32 + (l >> 4) * 8) * 2;
            bf16x8 af[4];
            #pragma unroll
            for (int fr = 0; fr < 4; ++fr) {
                int r = fr * 16 + (l & 15);
                af[fr] = *(const bf16x8*)(AswB + ((r * 128 + koff) ^ ((r & 7) << 4)));
            }
            #pragma unroll
            for (int fr = 0; fr < 4; ++fr)
                #pragma unroll
                for (int fc = 0; fc < 3; ++fc)
                    acc[fr][fc] = __builtin_amdgcn_mfma_f32_16x16x32_bf16(af[fr], bfr[ks][fc], acc[fr][fc], 0, 0, 0);
        }
        if (i < 11) B_LOAD((i + 1) * 64)       // next-tile B loads fly during staging
    }
#undef STAGE_LOAD
#undef B_LOAD
#undef STAGE_STORE

    // epilogue: h2 = gelu(acc + b2); partial score over this wave's 48 cols
    float b2v[3], w3v[3];
    #pragma unroll
    for (int fc = 0; fc < 3; ++fc) {
        int col = w * 48 + fc * 16 + (l & 15);
        b2v[fc] = b2[col];
        w3v[fc] = W3[col];
    }
    #pragma unroll
    for (int fr = 0; fr < 4; ++fr) {
        #pragma unroll
        for (int j = 0; j < 4; ++j) {
            float pr = 0.f;
            #pragma unroll
            for (int fc = 0; fc < 3; ++fc)
                pr += gelu_fast(acc[fr][fc][j] + b2v[fc]) * w3v[fc];
            pr += __shfl_xor(pr, 1);
            pr += __shfl_xor(pr, 2);
            pr += __shfl_xor(pr, 4);
            pr += __shfl_xor(pr, 8);
            if ((l & 15) == 0)
                spart[w][fr * 16 + (l >> 4) * 4 + j] = pr;
        }
    }
    __syncthreads();
    if (t < 64) {
        int row = t;
        float v = spart[0][row] + spart[1][row] + spart[2][row] + spart[3][row]
                + spart[4][row] + spart[5][row] + spart[6][row] + spart[7][row] + b3[0];
        float sc = sigmoid_fast(v);
        float m = (row < nd) ? sc : 0.f;
        m = wave_max(m);
        if (t == 0) {
            float segw = (ns > 10) ? 1.f : 100.f;
            out[1056 + b * 32 + s] = segw * m;
        }
    }
}

// ---- cosine via MFMA on normalized bf16 rows: dscos[b,s] = max_{d<nd} (1-dot)/2 ----
// 32 blocks (one per b), 256 threads = 4 waves; wave w owns d-slice [w*16, w*16+16)
__global__ __launch_bounds__(256) void cos_mfma(const unsigned short* __restrict__ dnbf,
                                                const unsigned short* __restrict__ snbf,
                                                const int* __restrict__ ndoc,
                                                float* __restrict__ dscos) {
    __shared__ float sred[4][32];
    int t = threadIdx.x, l = t & 63, w = t >> 6;
    int b = blockIdx.x;
    const unsigned short* sb = snbf + b * 32 * 768;
    const unsigned short* db = dnbf + b * 64 * 768;
    int arow = l & 15, ak = (l >> 4) * 8;
    int d0 = w * 16;
    f32x4 acc0 = (f32x4)0.f, acc1 = (f32x4)0.f;
    #pragma unroll
    for (int k = 0; k < 768; k += 32) {
        bf16x8 a0 = *(const bf16x8*)(sb + arow * 768 + k + ak);
        bf16x8 a1 = *(const bf16x8*)(sb + (16 + arow) * 768 + k + ak);
        bf16x8 bb = *(const bf16x8*)(db + (d0 + arow) * 768 + k + ak);
        acc0 = __builtin_amdgcn_mfma_f32_16x16x32_bf16(a0, bb, acc0, 0, 0, 0);
        acc1 = __builtin_amdgcn_mfma_f32_16x16x32_bf16(a1, bb, acc1, 0, 0, 0);
    }
    int nd = ndoc[b];
    int d = d0 + (l & 15);
    float v0[4], v1[4];
    #pragma unroll
    for (int j = 0; j < 4; ++j) {
        v0[j] = (d < nd) ? (1.f - acc0[j]) * 0.5f : 0.f;
        v1[j] = (d < nd) ? (1.f - acc1[j]) * 0.5f : 0.f;
    }
    #pragma unroll
    for (int o = 1; o < 16; o <<= 1) {
        #pragma unroll
        for (int j = 0; j < 4; ++j) {
            v0[j] = fmaxf(v0[j], __shfl_xor(v0[j], o));
            v1[j] = fmaxf(v1[j], __shfl_xor(v1[j], o));
        }
    }
    if ((l & 15) == 0) {
        int srow = (l >> 4) * 4;
        #pragma unroll
        for (int j = 0; j < 4; ++j) {
            sred[w][srow + j] = v0[j];
            sred[w][16 + srow + j] = v1[j];
        }
    }
    __syncthreads();
    if (t < 32)
        dscos[b * 32 + t] = fmaxf(fmaxf(sred[0][t], sred[1][t]),
                                  fmaxf(sred[2][t], sred[3][t]));
}

// ---- finish: passthrough outputs + cos_prior reduction ----
__global__ __launch_bounds__(1024) void finish_k(const float* __restrict__ agg,
                                                 const float* __restrict__ tinst,
                                                 const int* __restrict__ nseg,
                                                 const float* __restrict__ dscos,
                                                 float* __restrict__ out) {
    __shared__ float red[16];
    int t = threadIdx.x, lane = t & 63, w = t >> 6;
    int b = t >> 5, s = t & 31;
    int ns = nseg[b];
    out[32 + t] = (s < ns) ? tinst[t] : 1.0f;
    if (t < 32) {
        out[t] = agg[t];
        out[2080 + t] = (float)nseg[t];
    }
    float pred = out[1056 + t];
    float v = (s < ns) ? fabsf(dscos[t] - pred) / (float)ns : 0.f;
    v = wave_sum(v);
    if (lane == 0) red[w] = v;
    __syncthreads();
    if (w == 0) {
        float x = (lane < 16) ? red[lane] : 0.f;
        x = wave_sum(x);
        if (lane == 0) out[2112] = x * (1.f / 32.f);
    }
}

extern "C" void kernel_launch(void* const* d_in, const int* in_sizes, int n_in,
                              void* d_out, int out_size, void* d_ws, size_t ws_size,
                              hipStream_t stream) {
    const float* doc   = (const float*)d_in[0];   // [32,64,768]
    const float* sume  = (const float*)d_in[1];   // [32,32,768]
    const int*   ndoc  = (const int*)d_in[2];     // [32]
    const int*   nseg  = (const int*)d_in[3];     // [32]
    const float* agg   = (const float*)d_in[4];   // [32]
    const float* tinst = (const float*)d_in[5];   // [32,32]
    const float* W1    = (const float*)d_in[6];   // [1536,768]
    const float* b1    = (const float*)d_in[7];   // [768]
    const float* W2    = (const float*)d_in[8];   // [768,384]
    const float* b2    = (const float*)d_in[9];   // [384]
    const float* W3    = (const float*)d_in[10];  // [384,1]
    const float* b3    = (const float*)d_in[11];  // [1]
    float* out = (float*)d_out;
    char* ws = (char*)d_ws;

    float* hd    = (float*)(ws);                              // 2048*768 f32
    float* hs    = (float*)(ws + 6291456);                    // 1024*768 f32
    unsigned short* W1t  = (unsigned short*)(ws + 9437184);   // [768][1536] bf16
    unsigned short* W2t  = (unsigned short*)(ws + 11796480);  // [384][768] bf16
    unsigned short* dnbf = (unsigned short*)(ws + 12386304);  // [2048][768] bf16 normalized
    unsigned short* snbf = (unsigned short*)(ws + 15532032);  // [1024][768] bf16 normalized
    float* dscos = (float*)(ws + 17104896);                   // 1024 f32

    prep_all<<<1128, 256, 0, stream>>>(W1, W2, doc, sume, W1t, W2t, dnbf, snbf);
    gemm1<<<dim3(6, 24), 256, 0, stream>>>(doc, sume, W1t, hd, hs);
    score_mfma<<<1024, 512, 0, stream>>>(hd, hs, b1, W2t, b2, W3, b3, ndoc, nseg, out);
    cos_mfma<<<32, 256, 0, stream>>>(dnbf, snbf, ndoc, dscos);
    finish_k<<<1, 1024, 0, stream>>>(agg, tinst, nseg, dscos, out);
}

// Round 6
// 126.908 us; speedup vs baseline: 2.4301x; 1.1298x over previous
//
#include <hip/hip_runtime.h>
#include <hip/hip_bf16.h>
#include <math.h>

// Shapes: B=32, S=32, D=64, E=768
// out layout (floats): [0,32) agg | [32,1056) target_instance | [1056,2080) pred
//                      | [2080,2112) num_seg (as float) | [2112] cos_prior

typedef __bf16 bf16x8 __attribute__((ext_vector_type(8)));
typedef float f32x4 __attribute__((ext_vector_type(4)));

__device__ __forceinline__ unsigned short f2bf(float x) {
    unsigned int u = __float_as_uint(x);
    u = (u + 0x7fffu + ((u >> 16) & 1u)) >> 16;
    return (unsigned short)u;
}
// tanh-form GELU: x * sigmoid(1.5957691*x + 0.0713548*x^3); max abs err ~1e-3 vs erf form
__device__ __forceinline__ float gelu_fast(float x) {
    float u2 = x * fmaf(x * x, 0.0713548162726f, 1.5957691216057308f);
    return __fdividef(x, 1.0f + __expf(-u2));
}
__device__ __forceinline__ float sigmoid_fast(float x) {
    return __fdividef(1.0f, 1.0f + __expf(-x));
}
__device__ __forceinline__ float wave_sum(float v) {
    for (int o = 32; o; o >>= 1) v += __shfl_xor(v, o);
    return v;
}
__device__ __forceinline__ float wave_max(float v) {
    for (int o = 32; o; o >>= 1) v = fmaxf(v, __shfl_xor(v, o));
    return v;
}

// ---- prep: W1^T bf16, W2^T bf16, normalized-row bf16 copies (for MFMA cosine) ----
// blocks [0,288): W1 transpose ; [288,360): W2 transpose ; [360,1128): normalize rows
__global__ __launch_bounds__(256) void prep_all(const float* __restrict__ W1,
                                                const float* __restrict__ W2,
                                                const float* __restrict__ doc,
                                                const float* __restrict__ sume,
                                                unsigned short* __restrict__ W1t,
                                                unsigned short* __restrict__ W2t,
                                                unsigned short* __restrict__ dnbf,
                                                unsigned short* __restrict__ snbf) {
    int id = blockIdx.x;
    int t = threadIdx.x;
    if (id < 360) {
        __shared__ float tile[64][65];
        const float* in; unsigned short* outp; int R, C, bx, by;
        if (id < 288) { in = W1; outp = W1t; R = 1536; C = 768; bx = id % 12; by = id / 12; }
        else { int i2 = id - 288; in = W2; outp = W2t; R = 768; C = 384; bx = i2 % 6; by = i2 / 6; }
        int r0 = by * 64, c0 = bx * 64;
        #pragma unroll
        for (int p = 0; p < 16; ++p) {
            int r = p * 4 + (t >> 6), c = t & 63;
            tile[r][c] = in[(r0 + r) * C + c0 + c];
        }
        __syncthreads();
        #pragma unroll
        for (int p = 0; p < 16; ++p) {
            int cc = p * 4 + (t >> 6), rr = t & 63;
            outp[(c0 + cc) * R + r0 + rr] = f2bf(tile[rr][cc]);
        }
    } else {
        int row = (id - 360) * 4 + (t >> 6);
        int lane = t & 63;
        const float* p; unsigned short* dst;
        if (row < 2048) { p = doc + row * 768; dst = dnbf + row * 768; }
        else            { p = sume + (row - 2048) * 768; dst = snbf + (row - 2048) * 768; }
        const float* pp = p + lane * 12;
        float4 a0 = *(const float4*)(pp);
        float4 a1 = *(const float4*)(pp + 4);
        float4 a2 = *(const float4*)(pp + 8);
        float s = a0.x*a0.x + a0.y*a0.y + a0.z*a0.z + a0.w*a0.w
                + a1.x*a1.x + a1.y*a1.y + a1.z*a1.z + a1.w*a1.w
                + a2.x*a2.x + a2.y*a2.y + a2.z*a2.z + a2.w*a2.w;
        s = wave_sum(s);
        float r = rsqrtf(fmaxf(s, 1e-12f));
        unsigned short* dd = dst + lane * 12;
        dd[0]  = f2bf(a0.x * r); dd[1]  = f2bf(a0.y * r);
        dd[2]  = f2bf(a0.z * r); dd[3]  = f2bf(a0.w * r);
        dd[4]  = f2bf(a1.x * r); dd[5]  = f2bf(a1.y * r);
        dd[6]  = f2bf(a1.z * r); dd[7]  = f2bf(a1.w * r);
        dd[8]  = f2bf(a2.x * r); dd[9]  = f2bf(a2.y * r);
        dd[10] = f2bf(a2.z * r); dd[11] = f2bf(a2.w * r);
    }
}

// ---- stage-1 GEMM: [doc;sum] @ W1 -> hd/hs (bf16 out). 128x64 tile, 288 blocks ----
__global__ __launch_bounds__(256) void gemm1(const float* __restrict__ doc,
                                             const float* __restrict__ sume,
                                             const unsigned short* __restrict__ W1t,
                                             unsigned short* __restrict__ hd,
                                             unsigned short* __restrict__ hs) {
    __shared__ __align__(16) unsigned short Asw[128 * 64];   // 16 KB
    __shared__ __align__(16) unsigned short Bsw[64 * 64];    // 8 KB
    int t = threadIdx.x;
    int row0 = blockIdx.y * 128, col0 = blockIdx.x * 64;
    bool is_doc = row0 < 2048;
    const float* A = is_doc ? (doc + row0 * 768) : (sume + (row0 - 2048) * 768);
    int kbase = is_doc ? 0 : 768;
    unsigned short* O = is_doc ? (hd + row0 * 768) : (hs + (row0 - 2048) * 768);

    int l = t & 63, w = t >> 6;
    int wr = w >> 1, wc = w & 1;          // 2 row-waves x 2 col-waves
    f32x4 acc[4][2];
    #pragma unroll
    for (int i = 0; i < 4; ++i)
        #pragma unroll
        for (int j = 0; j < 2; ++j) acc[i][j] = (f32x4)0.f;

    char* AB = (char*)Asw;
    char* BB = (char*)Bsw;
    for (int kt = 0; kt < 768; kt += 64) {
        __syncthreads();
        #pragma unroll
        for (int p = 0; p < 4; ++p) {
            int r = p * 32 + (t >> 3);
            int ko = (t & 7) * 8;
            float4 f0 = *(const float4*)(A + r * 768 + kt + ko);
            float4 f1 = *(const float4*)(A + r * 768 + kt + ko + 4);
            __hip_bfloat162 p0 = __float22bfloat162_rn(make_float2(f0.x, f0.y));
            __hip_bfloat162 p1 = __float22bfloat162_rn(make_float2(f0.z, f0.w));
            __hip_bfloat162 p2 = __float22bfloat162_rn(make_float2(f1.x, f1.y));
            __hip_bfloat162 p3 = __float22bfloat162_rn(make_float2(f1.z, f1.w));
            uint4 v = make_uint4(*(unsigned int*)&p0, *(unsigned int*)&p1,
                                 *(unsigned int*)&p2, *(unsigned int*)&p3);
            int byte = (r * 128 + ko * 2) ^ ((r & 7) << 4);
            *(uint4*)(AB + byte) = v;
        }
        #pragma unroll
        for (int p = 0; p < 2; ++p) {
            int r = p * 32 + (t >> 3);
            int ko = (t & 7) * 8;
            bf16x8 bv = *(const bf16x8*)(W1t + (col0 + r) * 1536 + kbase + kt + ko);
            int byte = (r * 128 + ko * 2) ^ ((r & 7) << 4);
            *(bf16x8*)(BB + byte) = bv;
        }
        __syncthreads();
        #pragma unroll
        for (int ks = 0; ks < 2; ++ks) {
            int koff = (ks * 32 + (l >> 4) * 8) * 2;
            bf16x8 af[4], bfr[2];
            #pragma unroll
            for (int fr = 0; fr < 4; ++fr) {
                int r = wr * 64 + fr * 16 + (l & 15);
                af[fr] = *(const bf16x8*)(AB + ((r * 128 + koff) ^ ((r & 7) << 4)));
            }
            #pragma unroll
            for (int fc = 0; fc < 2; ++fc) {
                int n = wc * 32 + fc * 16 + (l & 15);
                bfr[fc] = *(const bf16x8*)(BB + ((n * 128 + koff) ^ ((n & 7) << 4)));
            }
            #pragma unroll
            for (int fr = 0; fr < 4; ++fr)
                #pragma unroll
                for (int fc = 0; fc < 2; ++fc)
                    acc[fr][fc] = __builtin_amdgcn_mfma_f32_16x16x32_bf16(af[fr], bfr[fc], acc[fr][fc], 0, 0, 0);
        }
    }
    #pragma unroll
    for (int fr = 0; fr < 4; ++fr)
        #pragma unroll
        for (int fc = 0; fc < 2; ++fc)
            #pragma unroll
            for (int j = 0; j < 4; ++j) {
                int r = wr * 64 + fr * 16 + (l >> 4) * 4 + j;
                int c = col0 + wc * 32 + fc * 16 + (l & 15);
                O[r * 768 + c] = f2bf(acc[fr][fc][j]);
            }
}

// ---- main fused kernel: blocks [0,1024) = score (one (b,s) each, 8 col-waves of
// 64x48), blocks [1024,1056) = MFMA cosine per b. Score: A-tile double-buffered
// (2x8KB), ONE barrier per K-tile; B-frags straight from L2; hd/hs are bf16.
__global__ __launch_bounds__(512, 2) void score_mfma(
    const unsigned short* __restrict__ hd, const unsigned short* __restrict__ hs,
    const float* __restrict__ b1, const unsigned short* __restrict__ W2t,
    const float* __restrict__ b2, const float* __restrict__ W3,
    const float* __restrict__ b3, const int* __restrict__ ndoc,
    const int* __restrict__ nseg, const unsigned short* __restrict__ dnbf,
    const unsigned short* __restrict__ snbf, float* __restrict__ out,
    float* __restrict__ dscos)
{
    __shared__ __align__(16) unsigned short Asw[2][64 * 64];   // 2 x 8 KB
    __shared__ float spart[8][64];                             // 2 KB
    __shared__ float sred[4][32];

    int t = threadIdx.x;
    int l = t & 63, w = t >> 6;

    if (blockIdx.x >= 1024) {
        // ---- cosine branch: one block per b ----
        int b = (int)blockIdx.x - 1024;
        if (w < 4) {
            const unsigned short* sb = snbf + b * 32 * 768;
            const unsigned short* db = dnbf + b * 64 * 768;
            int arow = l & 15, ak = (l >> 4) * 8;
            int d0 = w * 16;
            f32x4 acc0 = (f32x4)0.f, acc1 = (f32x4)0.f;
            #pragma unroll
            for (int k = 0; k < 768; k += 32) {
                bf16x8 a0 = *(const bf16x8*)(sb + arow * 768 + k + ak);
                bf16x8 a1 = *(const bf16x8*)(sb + (16 + arow) * 768 + k + ak);
                bf16x8 bb = *(const bf16x8*)(db + (d0 + arow) * 768 + k + ak);
                acc0 = __builtin_amdgcn_mfma_f32_16x16x32_bf16(a0, bb, acc0, 0, 0, 0);
                acc1 = __builtin_amdgcn_mfma_f32_16x16x32_bf16(a1, bb, acc1, 0, 0, 0);
            }
            int nd = ndoc[b];
            int d = d0 + (l & 15);
            float v0[4], v1[4];
            #pragma unroll
            for (int j = 0; j < 4; ++j) {
                v0[j] = (d < nd) ? (1.f - acc0[j]) * 0.5f : 0.f;
                v1[j] = (d < nd) ? (1.f - acc1[j]) * 0.5f : 0.f;
            }
            #pragma unroll
            for (int o = 1; o < 16; o <<= 1) {
                #pragma unroll
                for (int j = 0; j < 4; ++j) {
                    v0[j] = fmaxf(v0[j], __shfl_xor(v0[j], o));
                    v1[j] = fmaxf(v1[j], __shfl_xor(v1[j], o));
                }
            }
            if ((l & 15) == 0) {
                int srow = (l >> 4) * 4;
                #pragma unroll
                for (int j = 0; j < 4; ++j) {
                    sred[w][srow + j] = v0[j];
                    sred[w][16 + srow + j] = v1[j];
                }
            }
        }
        __syncthreads();
        if (t < 32)
            dscos[b * 32 + t] = fmaxf(fmaxf(sred[0][t], sred[1][t]),
                                      fmaxf(sred[2][t], sred[3][t]));
        return;
    }

    // ---- score branch ----
    // XCD-aware swizzle: 1024 blocks, 128 per XCD; the 32 s-blocks of one b share an XCD
    int lb = (int)(blockIdx.x & 7) * 128 + (int)(blockIdx.x >> 3);
    int b = lb >> 5, s = lb & 31;
    int nd = ndoc[b], ns = nseg[b];

    f32x4 acc[4][3];
    #pragma unroll
    for (int i = 0; i < 4; ++i)
        #pragma unroll
        for (int j = 0; j < 3; ++j) acc[i][j] = (f32x4)0.f;

    const unsigned short* hdB = hd + b * 64 * 768;
    const unsigned short* hsr = hs + (b * 32 + s) * 768;

    int rbase = t >> 5;          // 0..15 (A-row sub-index; rows p*16+rbase)
    int k0 = (t & 31) * 2;       // 0..62 (A k-pair)

    const unsigned short* bptr[3];
    #pragma unroll
    for (int fc = 0; fc < 3; ++fc) {
        int n = w * 48 + fc * 16 + (l & 15);
        bptr[fc] = W2t + n * 768 + (l >> 4) * 8;
    }

    unsigned int hvu[4]; float2 hav;
    bf16x8 bfr[2][3];

#define A_LOAD(KT)                                                              \
    {                                                                           \
        _Pragma("unroll")                                                       \
        for (int p = 0; p < 4; ++p)                                             \
            hvu[p] = *(const unsigned int*)(hdB + (p * 16 + rbase) * 768 + (KT) + k0); \
        unsigned int su = *(const unsigned int*)(hsr + (KT) + k0);              \
        float2 bb = *(const float2*)(b1 + (KT) + k0);                           \
        hav.x = __uint_as_float(su << 16) + bb.x;                               \
        hav.y = __uint_as_float(su & 0xffff0000u) + bb.y;                       \
    }

#define B_LOAD(KT)                                                              \
    {                                                                           \
        _Pragma("unroll")                                                       \
        for (int ks = 0; ks < 2; ++ks)                                          \
            _Pragma("unroll")                                                   \
            for (int fc = 0; fc < 3; ++fc)                                      \
                bfr[ks][fc] = *(const bf16x8*)(bptr[fc] + (KT) + ks * 32);      \
    }

#define STAGE_STORE(BUF)                                                        \
    {                                                                           \
        char* AB = (char*)Asw[BUF];                                             \
        _Pragma("unroll")                                                       \
        for (int p = 0; p < 4; ++p) {                                           \
            unsigned int u = hvu[p];                                            \
            float x0 = __uint_as_float(u << 16) + hav.x;                        \
            float x1 = __uint_as_float(u & 0xffff0000u) + hav.y;                \
            float g0 = gelu_fast(x0);                                           \
            float g1 = gelu_fast(x1);                                           \
            __hip_bfloat162 pk = __float22bfloat162_rn(make_float2(g0, g1));    \
            int r = p * 16 + rbase;                                             \
            int byte = (r * 128 + k0 * 2) ^ ((r & 7) << 4);                     \
            *(unsigned int*)(AB + byte) = *(unsigned int*)&pk;                  \
        }                                                                       \
    }

    // prologue: stage tile 0 into buf 0; preload tile-1 A regs
    A_LOAD(0)
    B_LOAD(0)
    STAGE_STORE(0)
    A_LOAD(64)
    __syncthreads();

    #pragma unroll 1
    for (int i = 0; i < 12; ++i) {
        int cur = i & 1;
        const char* AR = (const char*)Asw[cur];
        #pragma unroll
        for (int ks = 0; ks < 2; ++ks) {
            int koff = (ks * 32 + (l >> 4) * 8) * 2;
            bf16x8 af[4];
            #pragma unroll
            for (int fr = 0; fr < 4; ++fr) {
                int r = fr * 16 + (l & 15);
                af[fr] = *(const bf16x8*)(AR + ((r * 128 + koff) ^ ((r & 7) << 4)));
            }
            #pragma unroll
            for (int fr = 0; fr < 4; ++fr)
                #pragma unroll
                for (int fc = 0; fc < 3; ++fc)
                    acc[fr][fc] = __builtin_amdgcn_mfma_f32_16x16x32_bf16(af[fr], bfr[ks][fc], acc[fr][fc], 0, 0, 0);
        }
        if (i < 11) {
            B_LOAD((i + 1) * 64)          // refill B regs; L2 latency hides under gelu
            STAGE_STORE(cur ^ 1)          // gelu tile i+1 -> other buffer (overlaps MFMA drain)
            if (i < 10) A_LOAD((i + 2) * 64)
        }
        __syncthreads();                  // tile i+1 visible; all waves done reading buf cur
    }
#undef A_LOAD
#undef B_LOAD
#undef STAGE_STORE

    // epilogue: h2 = gelu(acc + b2); partial score over this wave's 48 cols
    float b2v[3], w3v[3];
    #pragma unroll
    for (int fc = 0; fc < 3; ++fc) {
        int col = w * 48 + fc * 16 + (l & 15);
        b2v[fc] = b2[col];
        w3v[fc] = W3[col];
    }
    #pragma unroll
    for (int fr = 0; fr < 4; ++fr) {
        #pragma unroll
        for (int j = 0; j < 4; ++j) {
            float pr = 0.f;
            #pragma unroll
            for (int fc = 0; fc < 3; ++fc)
                pr += gelu_fast(acc[fr][fc][j] + b2v[fc]) * w3v[fc];
            pr += __shfl_xor(pr, 1);
            pr += __shfl_xor(pr, 2);
            pr += __shfl_xor(pr, 4);
            pr += __shfl_xor(pr, 8);
            if ((l & 15) == 0)
                spart[w][fr * 16 + (l >> 4) * 4 + j] = pr;
        }
    }
    __syncthreads();
    if (t < 64) {
        int row = t;
        float v = spart[0][row] + spart[1][row] + spart[2][row] + spart[3][row]
                + spart[4][row] + spart[5][row] + spart[6][row] + spart[7][row] + b3[0];
        float sc = sigmoid_fast(v);
        float m = (row < nd) ? sc : 0.f;
        m = wave_max(m);
        if (t == 0) {
            float segw = (ns > 10) ? 1.f : 100.f;
            out[1056 + b * 32 + s] = segw * m;
        }
    }
}

// ---- finish: passthrough outputs + cos_prior reduction ----
__global__ __launch_bounds__(1024) void finish_k(const float* __restrict__ agg,
                                                 const float* __restrict__ tinst,
                                                 const int* __restrict__ nseg,
                                                 const float* __restrict__ dscos,
                                                 float* __restrict__ out) {
    __shared__ float red[16];
    int t = threadIdx.x, lane = t & 63, w = t >> 6;
    int b = t >> 5, s = t & 31;
    int ns = nseg[b];
    out[32 + t] = (s < ns) ? tinst[t] : 1.0f;
    if (t < 32) {
        out[t] = agg[t];
        out[2080 + t] = (float)nseg[t];
    }
    float pred = out[1056 + t];
    float v = (s < ns) ? fabsf(dscos[t] - pred) / (float)ns : 0.f;
    v = wave_sum(v);
    if (lane == 0) red[w] = v;
    __syncthreads();
    if (w == 0) {
        float x = (lane < 16) ? red[lane] : 0.f;
        x = wave_sum(x);
        if (lane == 0) out[2112] = x * (1.f / 32.f);
    }
}

extern "C" void kernel_launch(void* const* d_in, const int* in_sizes, int n_in,
                              void* d_out, int out_size, void* d_ws, size_t ws_size,
                              hipStream_t stream) {
    const float* doc   = (const float*)d_in[0];   // [32,64,768]
    const float* sume  = (const float*)d_in[1];   // [32,32,768]
    const int*   ndoc  = (const int*)d_in[2];     // [32]
    const int*   nseg  = (const int*)d_in[3];     // [32]
    const float* agg   = (const float*)d_in[4];   // [32]
    const float* tinst = (const float*)d_in[5];   // [32,32]
    const float* W1    = (const float*)d_in[6];   // [1536,768]
    const float* b1    = (const float*)d_in[7];   // [768]
    const float* W2    = (const float*)d_in[8];   // [768,384]
    const float* b2    = (const float*)d_in[9];   // [384]
    const float* W3    = (const float*)d_in[10];  // [384,1]
    const float* b3    = (const float*)d_in[11];  // [1]
    float* out = (float*)d_out;
    char* ws = (char*)d_ws;

    unsigned short* hd   = (unsigned short*)(ws);             // [2048][768] bf16
    unsigned short* hs   = (unsigned short*)(ws + 3145728);   // [1024][768] bf16
    unsigned short* W1t  = (unsigned short*)(ws + 4718592);   // [768][1536] bf16
    unsigned short* W2t  = (unsigned short*)(ws + 7077888);   // [384][768] bf16
    unsigned short* dnbf = (unsigned short*)(ws + 7667712);   // [2048][768] bf16 normalized
    unsigned short* snbf = (unsigned short*)(ws + 10813440);  // [1024][768] bf16 normalized
    float* dscos = (float*)(ws + 12386304);                   // 1024 f32

    prep_all<<<1128, 256, 0, stream>>>(W1, W2, doc, sume, W1t, W2t, dnbf, snbf);
    gemm1<<<dim3(12, 24), 256, 0, stream>>>(doc, sume, W1t, hd, hs);
    score_mfma<<<1056, 512, 0, stream>>>(hd, hs, b1, W2t, b2, W3, b3, ndoc, nseg,
                                         dnbf, snbf, out, dscos);
    finish_k<<<1, 1024, 0, stream>>>(agg, tinst, nseg, dscos, out);
}